// Round 2
// baseline (111.618 us; speedup 1.0000x reference)
//
#include <hip/hip_runtime.h>
#include <math.h>

#define B_SZ 1024
#define C_SZ 1000
#define H_SZ 512

// ws layout (bytes):
//   [0,     4096)  int      jv[1024]     argmax index per batch row
//   [4096,  8192)  float    ymax[1024]   row max of y
//   [8192, 12288)  float    wnorm[1000]  ||w_c||^2 (fp32)
//   [12288,16384)  unsigned ybot[1024]   order-encoded running max of y_bot
//   [16384,16512)  unsigned cnt[32]      per-b-tile completion counters
//   [20480, +1MB)  short    wbf[1000*512] bf16 copy of w

typedef __attribute__((ext_vector_type(8))) short bf16x8;
typedef __attribute__((ext_vector_type(4))) float f32x4;

__device__ __forceinline__ unsigned enc_f(float f) {
    unsigned u = __float_as_uint(f);
    return (u & 0x80000000u) ? ~u : (u | 0x80000000u);
}
__device__ __forceinline__ float dec_f(unsigned u) {
    return (u & 0x80000000u) ? __uint_as_float(u ^ 0x80000000u)
                             : __uint_as_float(~u);
}
#define ENC_NEG_INF 0x007FFFFFu  // enc(-inf)

// ---------------------------------------------------------------------------
// K1 prep, role by blockIdx.x:
//   [0,250):    wnorm + f32->bf16 convert, 4 w-rows per block (1 wave/row)
//   [250,1274): argmax/max of one y row + coalesced y->out copy + inits
__global__ __launch_bounds__(256) void k_prep(
    const float* __restrict__ y, const float* __restrict__ w,
    int* __restrict__ jv, float* __restrict__ ymax,
    float* __restrict__ wnorm, unsigned* __restrict__ ybot,
    unsigned* __restrict__ cnt, short* __restrict__ wbf,
    float* __restrict__ out) {
    const int r = blockIdx.x;
    const int tid = threadIdx.x;
    if (r < 250) {
        const int wave = tid >> 6, lane = tid & 63;
        const int c = r * 4 + wave;
        const float* row = w + c * H_SZ;
        float4 a = *(const float4*)(row + lane * 8);
        float4 b = *(const float4*)(row + lane * 8 + 4);
        float f[8] = {a.x, a.y, a.z, a.w, b.x, b.y, b.z, b.w};
        unsigned short u[8];
        float s = 0.f;
#pragma unroll
        for (int i = 0; i < 8; ++i) {
            s += f[i] * f[i];
            unsigned v = __float_as_uint(f[i]);
            v += 0x7fffu + ((v >> 16) & 1u);  // RNE
            u[i] = (unsigned short)(v >> 16);
        }
        uint4 pk;
        pk.x = (unsigned)u[0] | ((unsigned)u[1] << 16);
        pk.y = (unsigned)u[2] | ((unsigned)u[3] << 16);
        pk.z = (unsigned)u[4] | ((unsigned)u[5] << 16);
        pk.w = (unsigned)u[6] | ((unsigned)u[7] << 16);
        *(uint4*)(wbf + c * H_SZ + lane * 8) = pk;
#pragma unroll
        for (int off = 32; off; off >>= 1) s += __shfl_down(s, off, 64);
        if (lane == 0) wnorm[c] = s;
    } else {
        const int b = r - 250;
        const float* yrow = y + b * C_SZ;
        float* orow = out + b * (C_SZ + 1);
        float best = -INFINITY;
        int bidx = 0x7fffffff;
        // 250 float4 loads cover the row; threads 250..255 idle here.
        if (tid < 250) {
            float4 v = *(const float4*)(yrow + tid * 4);
            float e[4] = {v.x, v.y, v.z, v.w};
#pragma unroll
            for (int i = 0; i < 4; ++i) {
                orow[tid * 4 + i] = e[i];
                if (e[i] > best) { best = e[i]; bidx = tid * 4 + i; }
            }
        }
        // wave reduce (max, first index on ties)
        const int lane = tid & 63;
#pragma unroll
        for (int off = 32; off; off >>= 1) {
            float ov = __shfl_down(best, off, 64);
            int oi = __shfl_down(bidx, off, 64);
            if (ov > best || (ov == best && oi < bidx)) { best = ov; bidx = oi; }
        }
        __shared__ float sv[4];
        __shared__ int si[4];
        if (lane == 0) { sv[tid >> 6] = best; si[tid >> 6] = bidx; }
        __syncthreads();
        if (tid == 0) {
            float bv = sv[0]; int bi = si[0];
#pragma unroll
            for (int k = 1; k < 4; ++k) {
                if (sv[k] > bv || (sv[k] == bv && si[k] < bi)) { bv = sv[k]; bi = si[k]; }
            }
            jv[b] = bi;
            ymax[b] = bv;
            ybot[b] = ENC_NEG_INF;
        }
        if (b == 0 && tid < 32) cnt[tid] = 0u;
    }
}

// ---------------------------------------------------------------------------
// K2: gathered bf16 MFMA GEMM + fused epilogue + last-block y_bot write.
// Block tile 32(b) x 32(c); 4 waves, each one 16x16 mfma_f32_16x16x32_bf16.
// Fragments loaded directly from L2-resident wbf (16B/lane), no LDS.
__global__ __launch_bounds__(256) void k_main(
    const float* __restrict__ y, const short* __restrict__ wbf,
    const float* __restrict__ eps_p, const float* __restrict__ lip_p,
    const int* __restrict__ jv, const float* __restrict__ ymax,
    const float* __restrict__ wnorm, unsigned* __restrict__ ybot,
    unsigned* __restrict__ cnt, float* __restrict__ out) {
    const int t = threadIdx.x;
    const int wave = t >> 6, lane = t & 63;
    const int col = lane & 15, quad = lane >> 4;
    const int by = blockIdx.y, bx = blockIdx.x;
    const int b0 = by * 32 + (wave >> 1) * 16;
    const int c0 = bx * 32 + (wave & 1) * 16;

    const int arow = jv[b0 + col];                 // gathered A row for m=col
    const int ccol = c0 + col;
    const int crow = ccol < C_SZ ? ccol : C_SZ - 1;
    const short* ap = wbf + arow * H_SZ + quad * 8;
    const short* bp = wbf + crow * H_SZ + quad * 8;

    f32x4 acc = {0.f, 0.f, 0.f, 0.f};
    bf16x8 acur = *(const bf16x8*)ap;
    bf16x8 bcur = *(const bf16x8*)bp;
#pragma unroll
    for (int it = 0; it < 15; ++it) {
        bf16x8 anx = *(const bf16x8*)(ap + (it + 1) * 32);
        bf16x8 bnx = *(const bf16x8*)(bp + (it + 1) * 32);
        acc = __builtin_amdgcn_mfma_f32_16x16x32_bf16(acur, bcur, acc, 0, 0, 0);
        acur = anx;
        bcur = bnx;
    }
    acc = __builtin_amdgcn_mfma_f32_16x16x32_bf16(acur, bcur, acc, 0, 0, 0);

    // Epilogue. C/D layout: col=lane&15, row=quad*4+reg.
    const float eps = *eps_p;
    const float L = *lip_p;
    const float L2 = L * L;
    const float nc = wnorm[crow];
    float rmax[4];
#pragma unroll
    for (int i = 0; i < 4; ++i) {
        const int b = b0 + quad * 4 + i;
        const float nj = wnorm[jv[b]];
        const float ym = ymax[b];
        float cand = -INFINITY;
        if (ccol < C_SZ) {
            const float yv = y[b * C_SZ + ccol];
            const float sq = L2 * (nj + nc - 2.0f * acc[i]);
            const float K = sq > 0.f ? sqrtf(sq) : 0.f;
            cand = (yv == ym) ? -INFINITY : yv + eps * K;
        }
        rmax[i] = cand;
    }
    // max over the 16 cols (lanes sharing a quad)
#pragma unroll
    for (int off = 8; off; off >>= 1)
#pragma unroll
        for (int i = 0; i < 4; ++i)
            rmax[i] = fmaxf(rmax[i], __shfl_xor(rmax[i], off, 64));
    if (col == 0) {
#pragma unroll
        for (int i = 0; i < 4; ++i)
            atomicMax(&ybot[b0 + quad * 4 + i], enc_f(rmax[i]));
    }

    // Last c-tile block for this b-tile row writes the y_bot column.
    __shared__ unsigned slast;
    __syncthreads();
    if (t == 0) {
        __threadfence();
        slast = atomicAdd(&cnt[by], 1u);
    }
    __syncthreads();
    if (slast == 31u) {
        __threadfence();
        if (t < 32) {
            unsigned e = atomicMax(&ybot[by * 32 + t], 0u);  // atomic read
            out[(by * 32 + t) * (C_SZ + 1) + C_SZ] = dec_f(e);
        }
    }
}

// ---------------------------------------------------------------------------
extern "C" void kernel_launch(void* const* d_in, const int* in_sizes, int n_in,
                              void* d_out, int out_size, void* d_ws,
                              size_t ws_size, hipStream_t stream) {
    const float* y = (const float*)d_in[0];
    const float* w = (const float*)d_in[1];
    const float* eps = (const float*)d_in[2];
    const float* lip = (const float*)d_in[3];
    float* out = (float*)d_out;

    char* ws = (char*)d_ws;
    int* jv = (int*)ws;
    float* ymax = (float*)(ws + 4096);
    float* wnorm = (float*)(ws + 8192);
    unsigned* ybot = (unsigned*)(ws + 12288);
    unsigned* cnt = (unsigned*)(ws + 16384);
    short* wbf = (short*)(ws + 20480);

    k_prep<<<250 + B_SZ, 256, 0, stream>>>(y, w, jv, ymax, wnorm, ybot, cnt,
                                           wbf, out);
    k_main<<<dim3(32, 32), 256, 0, stream>>>(y, wbf, eps, lip, jv, ymax, wnorm,
                                             ybot, cnt, out);
}

// Round 3
// 88.615 us; speedup vs baseline: 1.2596x; 1.2596x over previous
//
#include <hip/hip_runtime.h>
#include <math.h>

#define B_SZ 1024
#define C_SZ 1000
#define H_SZ 512

// ws layout (bytes):
//   [0,     4096)  int      jv[1024]     argmax index per batch row
//   [4096,  8192)  float    ymax[1024]   row max of y
//   [8192, 12288)  float    wnorm[1000]  ||w_c||^2 (fp32)
//   [12288,16384)  unsigned ybot[1024]   order-encoded running max of y_bot
//   [20480, +1MB)  short    wbf[1000*512] bf16 copy of w

typedef __attribute__((ext_vector_type(8))) short bf16x8;
typedef __attribute__((ext_vector_type(4))) float f32x4;

__device__ __forceinline__ unsigned enc_f(float f) {
    unsigned u = __float_as_uint(f);
    return (u & 0x80000000u) ? ~u : (u | 0x80000000u);
}
__device__ __forceinline__ float dec_f(unsigned u) {
    return (u & 0x80000000u) ? __uint_as_float(u ^ 0x80000000u)
                             : __uint_as_float(~u);
}
#define ENC_NEG_INF 0x007FFFFFu  // enc(-inf)

// ---------------------------------------------------------------------------
// K1 prep, role by blockIdx.x:
//   [0,250):    wnorm + f32->bf16 convert, 4 w-rows per block (1 wave/row)
//   [250,1274): argmax/max of one y row + coalesced y->out copy + inits
__global__ __launch_bounds__(256) void k_prep(
    const float* __restrict__ y, const float* __restrict__ w,
    int* __restrict__ jv, float* __restrict__ ymax,
    float* __restrict__ wnorm, unsigned* __restrict__ ybot,
    short* __restrict__ wbf, float* __restrict__ out) {
    const int r = blockIdx.x;
    const int tid = threadIdx.x;
    if (r < 250) {
        const int wave = tid >> 6, lane = tid & 63;
        const int c = r * 4 + wave;
        const float* row = w + c * H_SZ;
        float4 a = *(const float4*)(row + lane * 8);
        float4 b = *(const float4*)(row + lane * 8 + 4);
        float f[8] = {a.x, a.y, a.z, a.w, b.x, b.y, b.z, b.w};
        unsigned short u[8];
        float s = 0.f;
#pragma unroll
        for (int i = 0; i < 8; ++i) {
            s += f[i] * f[i];
            unsigned v = __float_as_uint(f[i]);
            v += 0x7fffu + ((v >> 16) & 1u);  // RNE
            u[i] = (unsigned short)(v >> 16);
        }
        uint4 pk;
        pk.x = (unsigned)u[0] | ((unsigned)u[1] << 16);
        pk.y = (unsigned)u[2] | ((unsigned)u[3] << 16);
        pk.z = (unsigned)u[4] | ((unsigned)u[5] << 16);
        pk.w = (unsigned)u[6] | ((unsigned)u[7] << 16);
        *(uint4*)(wbf + c * H_SZ + lane * 8) = pk;
#pragma unroll
        for (int off = 32; off; off >>= 1) s += __shfl_down(s, off, 64);
        if (lane == 0) wnorm[c] = s;
    } else {
        const int b = r - 250;
        const float* yrow = y + b * C_SZ;
        float* orow = out + b * (C_SZ + 1);
        float best = -INFINITY;
        int bidx = 0x7fffffff;
        // 250 float4 loads cover the row; threads 250..255 idle here.
        if (tid < 250) {
            float4 v = *(const float4*)(yrow + tid * 4);
            float e[4] = {v.x, v.y, v.z, v.w};
#pragma unroll
            for (int i = 0; i < 4; ++i) {
                orow[tid * 4 + i] = e[i];
                if (e[i] > best) { best = e[i]; bidx = tid * 4 + i; }
            }
        }
        // wave reduce (max, first index on ties)
        const int lane = tid & 63;
#pragma unroll
        for (int off = 32; off; off >>= 1) {
            float ov = __shfl_down(best, off, 64);
            int oi = __shfl_down(bidx, off, 64);
            if (ov > best || (ov == best && oi < bidx)) { best = ov; bidx = oi; }
        }
        __shared__ float sv[4];
        __shared__ int si[4];
        if (lane == 0) { sv[tid >> 6] = best; si[tid >> 6] = bidx; }
        __syncthreads();
        if (tid == 0) {
            float bv = sv[0]; int bi = si[0];
#pragma unroll
            for (int k = 1; k < 4; ++k) {
                if (sv[k] > bv || (sv[k] == bv && si[k] < bi)) { bv = sv[k]; bi = si[k]; }
            }
            jv[b] = bi;
            ymax[b] = bv;
            ybot[b] = ENC_NEG_INF;
        }
    }
}

// ---------------------------------------------------------------------------
// K2: gathered bf16 MFMA GEMM + fused epilogue (atomicMax into ybot).
// Block tile 32(b) x 32(c); 4 waves, each one 16x16 mfma_f32_16x16x32_bf16.
// Fragments loaded directly from L2/L3-resident wbf (16B/lane), no LDS.
// NO fences / completion counters -- kernel boundary orders ybot for k_final.
__global__ __launch_bounds__(256) void k_main(
    const float* __restrict__ y, const short* __restrict__ wbf,
    const float* __restrict__ eps_p, const float* __restrict__ lip_p,
    const int* __restrict__ jv, const float* __restrict__ ymax,
    const float* __restrict__ wnorm, unsigned* __restrict__ ybot) {
    const int t = threadIdx.x;
    const int wave = t >> 6, lane = t & 63;
    const int col = lane & 15, quad = lane >> 4;
    const int by = blockIdx.y, bx = blockIdx.x;
    const int b0 = by * 32 + (wave >> 1) * 16;
    const int c0 = bx * 32 + (wave & 1) * 16;

    const int arow = jv[b0 + col];                 // gathered A row for m=col
    const int ccol = c0 + col;
    const int crow = ccol < C_SZ ? ccol : C_SZ - 1;
    const short* ap = wbf + arow * H_SZ + quad * 8;
    const short* bp = wbf + crow * H_SZ + quad * 8;

    f32x4 acc = {0.f, 0.f, 0.f, 0.f};
    bf16x8 acur = *(const bf16x8*)ap;
    bf16x8 bcur = *(const bf16x8*)bp;
#pragma unroll
    for (int it = 0; it < 15; ++it) {
        bf16x8 anx = *(const bf16x8*)(ap + (it + 1) * 32);
        bf16x8 bnx = *(const bf16x8*)(bp + (it + 1) * 32);
        acc = __builtin_amdgcn_mfma_f32_16x16x32_bf16(acur, bcur, acc, 0, 0, 0);
        acur = anx;
        bcur = bnx;
    }
    acc = __builtin_amdgcn_mfma_f32_16x16x32_bf16(acur, bcur, acc, 0, 0, 0);

    // Epilogue. C/D layout: col=lane&15, row=quad*4+reg.
    const float eps = *eps_p;
    const float L = *lip_p;
    const float L2 = L * L;
    const float nc = wnorm[crow];
    float rmax[4];
#pragma unroll
    for (int i = 0; i < 4; ++i) {
        const int b = b0 + quad * 4 + i;
        const float nj = wnorm[jv[b]];
        const float ym = ymax[b];
        float cand = -INFINITY;
        if (ccol < C_SZ) {
            const float yv = y[b * C_SZ + ccol];
            const float sq = L2 * (nj + nc - 2.0f * acc[i]);
            const float K = sq > 0.f ? sqrtf(sq) : 0.f;
            cand = (yv == ym) ? -INFINITY : yv + eps * K;
        }
        rmax[i] = cand;
    }
    // max over the 16 cols (lanes sharing a quad)
#pragma unroll
    for (int off = 8; off; off >>= 1)
#pragma unroll
        for (int i = 0; i < 4; ++i)
            rmax[i] = fmaxf(rmax[i], __shfl_xor(rmax[i], off, 64));
    if (col == 0) {
#pragma unroll
        for (int i = 0; i < 4; ++i)
            atomicMax(&ybot[b0 + quad * 4 + i], enc_f(rmax[i]));
    }
}

// ---------------------------------------------------------------------------
// K3: decode y_bot into the last output column.
__global__ void k_final(const unsigned* __restrict__ ybot,
                        float* __restrict__ out) {
    int b = blockIdx.x * 256 + threadIdx.x;
    if (b < B_SZ) out[b * (C_SZ + 1) + C_SZ] = dec_f(ybot[b]);
}

// ---------------------------------------------------------------------------
extern "C" void kernel_launch(void* const* d_in, const int* in_sizes, int n_in,
                              void* d_out, int out_size, void* d_ws,
                              size_t ws_size, hipStream_t stream) {
    const float* y = (const float*)d_in[0];
    const float* w = (const float*)d_in[1];
    const float* eps = (const float*)d_in[2];
    const float* lip = (const float*)d_in[3];
    float* out = (float*)d_out;

    char* ws = (char*)d_ws;
    int* jv = (int*)ws;
    float* ymax = (float*)(ws + 4096);
    float* wnorm = (float*)(ws + 8192);
    unsigned* ybot = (unsigned*)(ws + 12288);
    short* wbf = (short*)(ws + 20480);

    k_prep<<<250 + B_SZ, 256, 0, stream>>>(y, w, jv, ymax, wnorm, ybot, wbf,
                                           out);
    k_main<<<dim3(32, 32), 256, 0, stream>>>(y, wbf, eps, lip, jv, ymax, wnorm,
                                             ybot);
    k_final<<<(B_SZ + 255) / 256, 256, 0, stream>>>(ybot, out);
}

// Round 4
// 84.517 us; speedup vs baseline: 1.3207x; 1.0485x over previous
//
#include <hip/hip_runtime.h>
#include <math.h>

#define B_SZ 1024
#define C_SZ 1000
#define H_SZ 512

// ws layout (bytes):
//   [0,      4096)   int      jv[1024]      argmax index per batch row
//   [4096,   8192)   float    ymax[1024]    row max of y
//   [8192,  12288)   float    wnorm[1000]   ||w_c||^2 (fp32)
//   [16384, 278528)  float    part[64][1024] per-(c-half)-strip row maxes
//   [524288,+1MB)    short    wbf[1000*512] bf16 copy of w

typedef __attribute__((ext_vector_type(8))) short bf16x8;
typedef __attribute__((ext_vector_type(4))) float f32x4;

// ---------------------------------------------------------------------------
// K1 prep, role by blockIdx.x:
//   [0,250):    wnorm + f32->bf16 convert, 4 w-rows per block (1 wave/row)
//   [250,1274): argmax/max of one y row + coalesced y->out copy
__global__ __launch_bounds__(256) void k_prep(
    const float* __restrict__ y, const float* __restrict__ w,
    int* __restrict__ jv, float* __restrict__ ymax,
    float* __restrict__ wnorm, short* __restrict__ wbf,
    float* __restrict__ out) {
    const int r = blockIdx.x;
    const int tid = threadIdx.x;
    if (r < 250) {
        const int wave = tid >> 6, lane = tid & 63;
        const int c = r * 4 + wave;
        const float* row = w + c * H_SZ;
        float4 a = *(const float4*)(row + lane * 8);
        float4 b = *(const float4*)(row + lane * 8 + 4);
        float f[8] = {a.x, a.y, a.z, a.w, b.x, b.y, b.z, b.w};
        unsigned short u[8];
        float s = 0.f;
#pragma unroll
        for (int i = 0; i < 8; ++i) {
            s += f[i] * f[i];
            unsigned v = __float_as_uint(f[i]);
            v += 0x7fffu + ((v >> 16) & 1u);  // RNE
            u[i] = (unsigned short)(v >> 16);
        }
        uint4 pk;
        pk.x = (unsigned)u[0] | ((unsigned)u[1] << 16);
        pk.y = (unsigned)u[2] | ((unsigned)u[3] << 16);
        pk.z = (unsigned)u[4] | ((unsigned)u[5] << 16);
        pk.w = (unsigned)u[6] | ((unsigned)u[7] << 16);
        *(uint4*)(wbf + c * H_SZ + lane * 8) = pk;
#pragma unroll
        for (int off = 32; off; off >>= 1) s += __shfl_down(s, off, 64);
        if (lane == 0) wnorm[c] = s;
    } else {
        const int b = r - 250;
        const float* yrow = y + b * C_SZ;
        float* orow = out + b * (C_SZ + 1);
        float best = -INFINITY;
        int bidx = 0x7fffffff;
        // 250 float4 loads cover the row; threads 250..255 idle here.
        if (tid < 250) {
            float4 v = *(const float4*)(yrow + tid * 4);
            float e[4] = {v.x, v.y, v.z, v.w};
#pragma unroll
            for (int i = 0; i < 4; ++i) {
                orow[tid * 4 + i] = e[i];
                if (e[i] > best) { best = e[i]; bidx = tid * 4 + i; }
            }
        }
        // wave reduce (max, first index on ties)
        const int lane = tid & 63;
#pragma unroll
        for (int off = 32; off; off >>= 1) {
            float ov = __shfl_down(best, off, 64);
            int oi = __shfl_down(bidx, off, 64);
            if (ov > best || (ov == best && oi < bidx)) { best = ov; bidx = oi; }
        }
        __shared__ float sv[4];
        __shared__ int si[4];
        if (lane == 0) { sv[tid >> 6] = best; si[tid >> 6] = bidx; }
        __syncthreads();
        if (tid == 0) {
            float bv = sv[0]; int bi = si[0];
#pragma unroll
            for (int k = 1; k < 4; ++k) {
                if (sv[k] > bv || (sv[k] == bv && si[k] < bi)) { bv = sv[k]; bi = si[k]; }
            }
            jv[b] = bi;
            ymax[b] = bv;
        }
    }
}

// ---------------------------------------------------------------------------
// K2: gathered bf16 MFMA GEMM + fused epilogue.
// Block tile 32(b) x 32(c); 4 waves, each one 16x16 mfma_f32_16x16x32_bf16.
// Fragments loaded directly from L2/L3-resident wbf (16B/lane), no LDS.
// NO atomics, NO fences: each (bx, c-half) writes its 32 partial row-maxes
// to a private slice of part[]; kernel boundary orders them for k_final.
__global__ __launch_bounds__(256) void k_main(
    const float* __restrict__ y, const short* __restrict__ wbf,
    const float* __restrict__ eps_p, const float* __restrict__ lip_p,
    const int* __restrict__ jv, const float* __restrict__ ymax,
    const float* __restrict__ wnorm, float* __restrict__ part) {
    const int t = threadIdx.x;
    const int wave = t >> 6, lane = t & 63;
    const int col = lane & 15, quad = lane >> 4;
    const int by = blockIdx.y, bx = blockIdx.x;
    const int b0 = by * 32 + (wave >> 1) * 16;
    const int half = wave & 1;
    const int c0 = bx * 32 + half * 16;

    const int arow = jv[b0 + col];                 // gathered A row for m=col
    const int ccol = c0 + col;
    const int crow = ccol < C_SZ ? ccol : C_SZ - 1;
    const short* ap = wbf + arow * H_SZ + quad * 8;
    const short* bp = wbf + crow * H_SZ + quad * 8;

    f32x4 acc = {0.f, 0.f, 0.f, 0.f};
    bf16x8 acur = *(const bf16x8*)ap;
    bf16x8 bcur = *(const bf16x8*)bp;
#pragma unroll
    for (int it = 0; it < 15; ++it) {
        bf16x8 anx = *(const bf16x8*)(ap + (it + 1) * 32);
        bf16x8 bnx = *(const bf16x8*)(bp + (it + 1) * 32);
        acc = __builtin_amdgcn_mfma_f32_16x16x32_bf16(acur, bcur, acc, 0, 0, 0);
        acur = anx;
        bcur = bnx;
    }
    acc = __builtin_amdgcn_mfma_f32_16x16x32_bf16(acur, bcur, acc, 0, 0, 0);

    // Epilogue. C/D layout: col=lane&15, row=quad*4+reg.
    const float eps = *eps_p;
    const float L = *lip_p;
    const float L2 = L * L;
    const float nc = wnorm[crow];
    float rmax[4];
#pragma unroll
    for (int i = 0; i < 4; ++i) {
        const int b = b0 + quad * 4 + i;
        const float nj = wnorm[jv[b]];
        const float ym = ymax[b];
        float cand = -INFINITY;
        if (ccol < C_SZ) {
            const float yv = y[b * C_SZ + ccol];
            const float sq = L2 * (nj + nc - 2.0f * acc[i]);
            const float K = sq > 0.f ? sqrtf(sq) : 0.f;
            cand = (yv == ym) ? -INFINITY : yv + eps * K;
        }
        rmax[i] = cand;
    }
    // max over the 16 cols (lanes sharing a quad)
#pragma unroll
    for (int off = 8; off; off >>= 1)
#pragma unroll
        for (int i = 0; i < 4; ++i)
            rmax[i] = fmaxf(rmax[i], __shfl_xor(rmax[i], off, 64));
    if (col == 0) {
        float* slice = part + (bx * 2 + half) * B_SZ;
#pragma unroll
        for (int i = 0; i < 4; ++i)
            slice[b0 + quad * 4 + i] = rmax[i];
    }
}

// ---------------------------------------------------------------------------
// K3: reduce the 64 per-strip partial maxes into the last output column.
__global__ void k_final(const float* __restrict__ part,
                        float* __restrict__ out) {
    int b = blockIdx.x * 256 + threadIdx.x;
    if (b >= B_SZ) return;
    float m = -INFINITY;
#pragma unroll
    for (int s = 0; s < 64; ++s) m = fmaxf(m, part[s * B_SZ + b]);
    out[b * (C_SZ + 1) + C_SZ] = m;
}

// ---------------------------------------------------------------------------
extern "C" void kernel_launch(void* const* d_in, const int* in_sizes, int n_in,
                              void* d_out, int out_size, void* d_ws,
                              size_t ws_size, hipStream_t stream) {
    const float* y = (const float*)d_in[0];
    const float* w = (const float*)d_in[1];
    const float* eps = (const float*)d_in[2];
    const float* lip = (const float*)d_in[3];
    float* out = (float*)d_out;

    char* ws = (char*)d_ws;
    int* jv = (int*)ws;
    float* ymax = (float*)(ws + 4096);
    float* wnorm = (float*)(ws + 8192);
    float* part = (float*)(ws + 16384);
    short* wbf = (short*)(ws + 524288);

    k_prep<<<250 + B_SZ, 256, 0, stream>>>(y, w, jv, ymax, wnorm, wbf, out);
    k_main<<<dim3(32, 32), 256, 0, stream>>>(y, wbf, eps, lip, jv, ymax, wnorm,
                                             part);
    k_final<<<(B_SZ + 255) / 256, 256, 0, stream>>>(part, out);
}

// Round 5
// 82.663 us; speedup vs baseline: 1.3503x; 1.0224x over previous
//
#include <hip/hip_runtime.h>
#include <math.h>

#define B_SZ 1024
#define C_SZ 1000
#define H_SZ 512

// ws layout (bytes):
//   [0,      4096)   int      jv[1024]       argmax index per batch row
//   [4096,   8192)   float    ymax[1024]     row max of y
//   [8192,  12288)   float    wnorm[1000]    ||w_c||^2 (fp32)
//   [16384,  81920)  float    part[16][1024] per-bx-strip row maxes
//   [524288,+1MB)    short    wbf[1000*512]  bf16 copy of w

typedef __attribute__((ext_vector_type(8))) short bf16x8;
typedef __attribute__((ext_vector_type(4))) float f32x4;

// ---------------------------------------------------------------------------
// K1 prep, role by blockIdx.x:
//   [0,250):    wnorm + f32->bf16 convert, 4 w-rows per block (1 wave/row)
//   [250,1274): argmax/max of one y row + coalesced y->out copy
__global__ __launch_bounds__(256) void k_prep(
    const float* __restrict__ y, const float* __restrict__ w,
    int* __restrict__ jv, float* __restrict__ ymax,
    float* __restrict__ wnorm, short* __restrict__ wbf,
    float* __restrict__ out) {
    const int r = blockIdx.x;
    const int tid = threadIdx.x;
    if (r < 250) {
        const int wave = tid >> 6, lane = tid & 63;
        const int c = r * 4 + wave;
        const float* row = w + c * H_SZ;
        float4 a = *(const float4*)(row + lane * 8);
        float4 b = *(const float4*)(row + lane * 8 + 4);
        float f[8] = {a.x, a.y, a.z, a.w, b.x, b.y, b.z, b.w};
        unsigned short u[8];
        float s = 0.f;
#pragma unroll
        for (int i = 0; i < 8; ++i) {
            s += f[i] * f[i];
            unsigned v = __float_as_uint(f[i]);
            v += 0x7fffu + ((v >> 16) & 1u);  // RNE
            u[i] = (unsigned short)(v >> 16);
        }
        uint4 pk;
        pk.x = (unsigned)u[0] | ((unsigned)u[1] << 16);
        pk.y = (unsigned)u[2] | ((unsigned)u[3] << 16);
        pk.z = (unsigned)u[4] | ((unsigned)u[5] << 16);
        pk.w = (unsigned)u[6] | ((unsigned)u[7] << 16);
        *(uint4*)(wbf + c * H_SZ + lane * 8) = pk;
#pragma unroll
        for (int off = 32; off; off >>= 1) s += __shfl_down(s, off, 64);
        if (lane == 0) wnorm[c] = s;
    } else {
        const int b = r - 250;
        const float* yrow = y + b * C_SZ;
        float* orow = out + b * (C_SZ + 1);
        float best = -INFINITY;
        int bidx = 0x7fffffff;
        if (tid < 250) {
            float4 v = *(const float4*)(yrow + tid * 4);
            float e[4] = {v.x, v.y, v.z, v.w};
#pragma unroll
            for (int i = 0; i < 4; ++i) {
                orow[tid * 4 + i] = e[i];
                if (e[i] > best) { best = e[i]; bidx = tid * 4 + i; }
            }
        }
        const int lane = tid & 63;
#pragma unroll
        for (int off = 32; off; off >>= 1) {
            float ov = __shfl_down(best, off, 64);
            int oi = __shfl_down(bidx, off, 64);
            if (ov > best || (ov == best && oi < bidx)) { best = ov; bidx = oi; }
        }
        __shared__ float sv[4];
        __shared__ int si[4];
        if (lane == 0) { sv[tid >> 6] = best; si[tid >> 6] = bidx; }
        __syncthreads();
        if (tid == 0) {
            float bv = sv[0]; int bi = si[0];
#pragma unroll
            for (int k = 1; k < 4; ++k) {
                if (sv[k] > bv || (sv[k] == bv && si[k] < bi)) { bv = sv[k]; bi = si[k]; }
            }
            jv[b] = bi;
            ymax[b] = bv;
        }
    }
}

// ---------------------------------------------------------------------------
// K2: LDS-staged gathered bf16 MFMA GEMM + fused epilogue.
// Block 64(b) x 64(c) x K512; K staged in 4 chunks of 128 (register-
// prefetched one chunk ahead). 4 waves; wave wv computes m-tile wv x all
// 4 c-tiles with mfma_f32_16x16x32_bf16 (layouts verified in R2-R4).
// Row stride 136 shorts (+8 pad): bank-group = (row + k16) % 8, 2-way = free.
#define KC 128          // k elements per chunk
#define RS 136          // LDS row stride in shorts
__global__ __launch_bounds__(256) void k_main(
    const float* __restrict__ y, const short* __restrict__ wbf,
    const float* __restrict__ eps_p, const float* __restrict__ lip_p,
    const int* __restrict__ jv, const float* __restrict__ ymax,
    const float* __restrict__ wnorm, float* __restrict__ part) {
    __shared__ __align__(16) short As[64 * RS];
    __shared__ __align__(16) short Bs[64 * RS];
    __shared__ int sjv[64];
    __shared__ float snj[64];
    __shared__ float sym[64];

    const int t = threadIdx.x;
    const int bx = blockIdx.x, by = blockIdx.y;
    const int b0 = by * 64, c0 = bx * 64;

    if (t < 64) {
        int j = jv[b0 + t];
        sjv[t] = j;
        snj[t] = wnorm[j];
        sym[t] = ymax[b0 + t];
    }
    __syncthreads();

    // Staging assignment: 4 threads per row, 4 passes -> 16 x 16B per row-chunk.
    const int srow = t >> 2;       // 0..63
    const int sseg = t & 3;
    int crow = c0 + srow; if (crow > C_SZ - 1) crow = C_SZ - 1;
    const short* agsrc = wbf + sjv[srow] * H_SZ;
    const short* bgsrc = wbf + crow * H_SZ;

    uint4 pa[4], pb[4];
    // prefetch chunk 0
#pragma unroll
    for (int p = 0; p < 4; ++p) {
        const int off = (sseg + p * 4) * 8;  // shorts within chunk
        pa[p] = *(const uint4*)(agsrc + off);
        pb[p] = *(const uint4*)(bgsrc + off);
    }

    const int wv = t >> 6, lane = t & 63;
    const int col = lane & 15, quad = lane >> 4;
    const short* ard = &As[(wv * 16 + col) * RS + quad * 8];
    const short* brd = &Bs[col * RS + quad * 8];

    f32x4 acc[4] = {{0.f, 0.f, 0.f, 0.f},
                    {0.f, 0.f, 0.f, 0.f},
                    {0.f, 0.f, 0.f, 0.f},
                    {0.f, 0.f, 0.f, 0.f}};

    for (int ch = 0; ch < 4; ++ch) {
        // write prefetched chunk to LDS
#pragma unroll
        for (int p = 0; p < 4; ++p) {
            const int off = (sseg + p * 4) * 8;
            *(uint4*)&As[srow * RS + off] = pa[p];
            *(uint4*)&Bs[srow * RS + off] = pb[p];
        }
        __syncthreads();
        // prefetch next chunk (global loads overlap MFMA compute below)
        if (ch < 3) {
            const int gbase = (ch + 1) * KC;
#pragma unroll
            for (int p = 0; p < 4; ++p) {
                const int off = gbase + (sseg + p * 4) * 8;
                pa[p] = *(const uint4*)(agsrc + off);
                pb[p] = *(const uint4*)(bgsrc + off);
            }
        }
        // compute: 4 k-steps of 32 per chunk
#pragma unroll
        for (int ks = 0; ks < 4; ++ks) {
            bf16x8 af = *(const bf16x8*)(ard + ks * 32);
#pragma unroll
            for (int ct = 0; ct < 4; ++ct) {
                bf16x8 bf = *(const bf16x8*)(brd + ct * 16 * RS + ks * 32);
                acc[ct] =
                    __builtin_amdgcn_mfma_f32_16x16x32_bf16(af, bf, acc[ct], 0, 0, 0);
            }
        }
        __syncthreads();  // compute done before next chunk's LDS overwrite
    }

    // Epilogue. C/D layout: col=lane&15, row=quad*4+reg.
    const float eps = *eps_p;
    const float L = *lip_p;
    const float L2 = L * L;
    float rmax[4];
#pragma unroll
    for (int i = 0; i < 4; ++i) {
        const int br = wv * 16 + quad * 4 + i;
        const int b = b0 + br;
        const float nj = snj[br];
        const float ym = sym[br];
        float m = -INFINITY;
#pragma unroll
        for (int ct = 0; ct < 4; ++ct) {
            const int cc = c0 + ct * 16 + col;
            if (cc < C_SZ) {
                const float yv = y[b * C_SZ + cc];
                const float nc = wnorm[cc];
                const float sq = L2 * (nj + nc - 2.0f * acc[ct][i]);
                const float K = sq > 0.f ? sqrtf(sq) : 0.f;
                const float cand = (yv == ym) ? -INFINITY : yv + eps * K;
                m = fmaxf(m, cand);
            }
        }
        rmax[i] = m;
    }
    // max over the 16 cols (bits 0..3 of lane)
#pragma unroll
    for (int off = 8; off; off >>= 1)
#pragma unroll
        for (int i = 0; i < 4; ++i)
            rmax[i] = fmaxf(rmax[i], __shfl_xor(rmax[i], off, 64));
    if (col == 0) {
        float* slice = part + bx * B_SZ;
#pragma unroll
        for (int i = 0; i < 4; ++i)
            slice[b0 + wv * 16 + quad * 4 + i] = rmax[i];
    }
}

// ---------------------------------------------------------------------------
// K3: reduce the 16 per-strip partial maxes into the last output column.
__global__ void k_final(const float* __restrict__ part,
                        float* __restrict__ out) {
    int b = blockIdx.x * 256 + threadIdx.x;
    if (b >= B_SZ) return;
    float m = -INFINITY;
#pragma unroll
    for (int s = 0; s < 16; ++s) m = fmaxf(m, part[s * B_SZ + b]);
    out[b * (C_SZ + 1) + C_SZ] = m;
}

// ---------------------------------------------------------------------------
extern "C" void kernel_launch(void* const* d_in, const int* in_sizes, int n_in,
                              void* d_out, int out_size, void* d_ws,
                              size_t ws_size, hipStream_t stream) {
    const float* y = (const float*)d_in[0];
    const float* w = (const float*)d_in[1];
    const float* eps = (const float*)d_in[2];
    const float* lip = (const float*)d_in[3];
    float* out = (float*)d_out;

    char* ws = (char*)d_ws;
    int* jv = (int*)ws;
    float* ymax = (float*)(ws + 4096);
    float* wnorm = (float*)(ws + 8192);
    float* part = (float*)(ws + 16384);
    short* wbf = (short*)(ws + 524288);

    k_prep<<<250 + B_SZ, 256, 0, stream>>>(y, w, jv, ymax, wnorm, wbf, out);
    k_main<<<dim3(16, 16), 256, 0, stream>>>(y, wbf, eps, lip, jv, ymax, wnorm,
                                             part);
    k_final<<<(B_SZ + 255) / 256, 256, 0, stream>>>(part, out);
}